// Round 12
// baseline (46.996 us; speedup 1.0000x reference)
//
#include <hip/hip_runtime.h>
#include <hip/hip_bf16.h>
#include <stdint.h>

#define C_ 400
#define TINV 10.0f
#define ALPHA_ 0.03f

typedef __bf16 bf16x8 __attribute__((ext_vector_type(8)));
typedef float f32x4 __attribute__((ext_vector_type(4)));

// ---- K0: convert features f32->bf16 (row-permuted new_r=(r%8)*512+r/8, float4
//          vectorized) + cross-entropy partials (8 rows/block) + counter reset.
//          (verified round-8 kernel)
__global__ __launch_bounds__(256) void k_prep(const float* __restrict__ feat,
                                              const float* __restrict__ predicts,
                                              const int* __restrict__ labels,
                                              uint16_t* __restrict__ featB,
                                              double* __restrict__ p_ce,
                                              unsigned int* __restrict__ counter) {
  __shared__ double smr[4];
  const int t = threadIdx.x, bid = blockIdx.x;
  const int lane = t & 63, w = t >> 6;
  if (bid == 0 && t == 0) counter[0] = 0;  // reset finalize counter each call

  int idx4 = bid * 256 + t;  // 131072 float4 tasks
  int nr = idx4 >> 5, d4 = idx4 & 31;
  int r = ((nr & 511) << 3) | (nr >> 9);
  float4 v = reinterpret_cast<const float4*>(feat)[r * 32 + d4];
  __hip_bfloat16 h0 = __float2bfloat16(v.x), h1 = __float2bfloat16(v.y),
                 h2 = __float2bfloat16(v.z), h3 = __float2bfloat16(v.w);
  ushort4 o;
  o.x = *(uint16_t*)&h0; o.y = *(uint16_t*)&h1;
  o.z = *(uint16_t*)&h2; o.w = *(uint16_t*)&h3;
  reinterpret_cast<ushort4*>(featB)[idx4] = o;

  double ce = 0.0;
#pragma unroll
  for (int s = 0; s < 2; ++s) {
    int row = bid * 8 + w * 2 + s;
    const float* pr = predicts + (size_t)row * C_;
    float mx = -3.0e38f;
    for (int k = lane; k < C_; k += 64) mx = fmaxf(mx, pr[k]);
#pragma unroll
    for (int o2 = 32; o2; o2 >>= 1) mx = fmaxf(mx, __shfl_xor(mx, o2));
    float sum = 0.f;
    for (int k = lane; k < C_; k += 64) sum += __expf(pr[k] - mx);
#pragma unroll
    for (int o2 = 32; o2; o2 >>= 1) sum += __shfl_xor(sum, o2);
    ce += (double)(__logf(sum) + mx - pr[labels[row]]);
  }
  if (lane == 0) smr[w] = ce;
  __syncthreads();
  if (t == 0) p_ce[bid] = smr[0] + smr[1] + smr[2] + smr[3];
}

// ---- K1: barrier-free Gram sweep. 2048 blocks; each of the 4 waves owns a
// DISJOINT 32-row x 64-col output tile (block = 32 rows x 256 cols). A and
// B fragments load directly from the L2-resident bf16 featB into registers:
// no LDS, no s_barrier, no redundant per-wave B traffic (the round-9 failure
// had 4x redundancy + per-step chains). Per-n B loads pipeline under the
// previous n's MFMA+exp. Power sums go to per-strip partial slots
// S1h/S2h[(g*8+jb)*8+strip]; partner/diag extraction identical to verified
// rounds (P written where (col&511)==(row&511); zeroed only when col==row).
__global__ __launch_bounds__(256, 4) void k_sweep(const uint16_t* __restrict__ featB,
                                                  float* __restrict__ S1h,
                                                  float* __restrict__ S2h,
                                                  float* __restrict__ P) {
  const int t = threadIdx.x, bid = blockIdx.x;
  const int lane = t & 63, w = t >> 6;
  const int r0 = lane & 15, kq = lane >> 4, rq = kq << 2;
  const char* fb = (const char*)featB;
  const int rc = bid >> 4, cb = bid & 15;
  const int rb = rc << 5;                   // 32 rows per block
  const int cstrip = (cb << 8) + (w << 6);  // this wave's 64-col strip
  const int jb = cstrip >> 9;               // 512-col pair-block
  const int strip = (cstrip >> 6) & 7;      // strip index within jb
  const int ib = rb >> 9;

  // A fragments: 2 row-groups x 4 K-chunks, direct from L2.
  bf16x8 a[2][4];
#pragma unroll
  for (int rg = 0; rg < 2; ++rg) {
    const size_t ra = (size_t)(rb + rg * 16 + r0) * 256 + kq * 16;
#pragma unroll
    for (int kk = 0; kk < 4; ++kk) a[rg][kk] = *(const bf16x8*)(fb + ra + kk * 64);
  }

  float s1[2][4], s2[2][4];
#pragma unroll
  for (int rg = 0; rg < 2; ++rg)
#pragma unroll
    for (int q = 0; q < 4; ++q) { s1[rg][q] = 0.f; s2[rg][q] = 0.f; }

#pragma unroll
  for (int n = 0; n < 4; ++n) {
    const int gcol = cstrip + n * 16 + r0;
    const size_t cbyte = (size_t)gcol * 256 + kq * 16;
    bf16x8 bn[4];
#pragma unroll
    for (int kk = 0; kk < 4; ++kk) bn[kk] = *(const bf16x8*)(fb + cbyte + kk * 64);
    f32x4 acc[2];
    acc[0] = (f32x4)0.0f;
    acc[1] = (f32x4)0.0f;
#pragma unroll
    for (int rg = 0; rg < 2; ++rg)
#pragma unroll
      for (int kk = 0; kk < 4; ++kk)
        acc[rg] = __builtin_amdgcn_mfma_f32_16x16x32_bf16(a[rg][kk], bn[kk],
                                                          acc[rg], 0, 0, 0);
#pragma unroll
    for (int rg = 0; rg < 2; ++rg)
#pragma unroll
      for (int q = 0; q < 4; ++q) {
        float e = __expf(acc[rg][q] * TINV);
        int grow = rb + rg * 16 + rq + q;
        if ((gcol & 511) == (grow & 511)) {
          P[(size_t)grow * 8 + jb] = e;      // partner (== Egg when jb==ib)
          if ((gcol >> 9) == ib) e = 0.f;    // exclude exact diagonal col==row
        }
        s1[rg][q] += e;
        s2[rg][q] += e * e;
      }
  }

#pragma unroll
  for (int rg = 0; rg < 2; ++rg)
#pragma unroll
    for (int q = 0; q < 4; ++q) {
      float v1 = s1[rg][q], v2 = s2[rg][q];
#pragma unroll
      for (int o2 = 1; o2 <= 8; o2 <<= 1) {
        v1 += __shfl_xor(v1, o2);
        v2 += __shfl_xor(v2, o2);
      }
      if (r0 == 0) {
        int grow = rb + rg * 16 + rq + q;
        size_t gi = ((size_t)grow * 8 + jb) * 8 + strip;
        S1h[gi] = v1;
        S2h[gi] = v2;
      }
    }
}

// ---- K2: closed-form NCE from strip power sums (S1,S2), 128 blocks;
// deterministic last-block finalize (atomic counter, reset by k_prep).
__global__ __launch_bounds__(256) void k_post(const float* __restrict__ S1h,
                                              const float* __restrict__ S2h,
                                              const float* __restrict__ P,
                                              const double* __restrict__ p_ce,
                                              double* __restrict__ p_nce,
                                              unsigned int* __restrict__ counter,
                                              float* __restrict__ out) {
  __shared__ double smr[4];
  __shared__ int isLast;
  const int t = threadIdx.x, b = blockIdx.x;
  const int lane = t & 63, w = t >> 6;
  const f32x4* S14 = (const f32x4*)S1h;
  const f32x4* S24 = (const f32x4*)S2h;
  double nce = 0.0;
  {
    int task = b * 256 + t;  // 0..32767
    int g = task >> 3, j = task & 7, i = g >> 9;
    size_t bi = ((size_t)g * 8 + i) * 2;  // in f32x4 units (8 floats/slot)
    f32x4 x0 = S14[bi], x1 = S14[bi + 1];
    f32x4 y0 = S24[bi], y1 = S24[bi + 1];
    float s1i = (x0[0] + x0[1] + x0[2] + x0[3]) + (x1[0] + x1[1] + x1[2] + x1[3]);
    float s2i = (y0[0] + y0[1] + y0[2] + y0[3]) + (y1[0] + y1[1] + y1[2] + y1[3]);
    float Egg = P[(size_t)g * 8 + i];
    float val;
    if (j != i) {
      size_t bj = ((size_t)g * 8 + j) * 2;
      f32x4 u0 = S14[bj], u1 = S14[bj + 1];
      f32x4 v0 = S24[bj], v1 = S24[bj + 1];
      float s1j = (u0[0] + u0[1] + u0[2] + u0[3]) + (u1[0] + u1[1] + u1[2] + u1[3]);
      float s2j = (v0[0] + v0[1] + v0[2] + v0[3]) + (v1[0] + v1[1] + v1[2] + v1[3]);
      float div = s1i + s1j;
      float inv = 1.f / div;
      float pmt = P[(size_t)g * 8 + j] * inv;
      float Ls = (s1i + s1j) + inv * (0.5f * (s2i + s2j));
      val = __logf(pmt) - __logf(1.f - pmt) - inv * Ls;
    } else {
      float div = 2.f * s1i + Egg;
      float inv = 1.f / div;
      float pmt = Egg * inv;
      float Ls = s1i + inv * (0.5f * s2i);
      val = 2.f * __logf(pmt) - 4.f * inv * Ls;
    }
    nce = (double)val;
  }
#pragma unroll
  for (int o2 = 32; o2; o2 >>= 1) nce += __shfl_xor(nce, o2);
  if (lane == 0) smr[w] = nce;
  __syncthreads();
  if (t == 0) {
    p_nce[b] = smr[0] + smr[1] + smr[2] + smr[3];
    __threadfence();
    unsigned int old = atomicAdd(counter, 1u);
    isLast = (old == 127u) ? 1 : 0;
  }
  __syncthreads();
  if (isLast) {
    __threadfence();
    double tn = (t < 128) ? p_nce[t] : 0.0;
    double tc = p_ce[t] + p_ce[t + 256];
#pragma unroll
    for (int o2 = 32; o2; o2 >>= 1) {
      tn += __shfl_xor(tn, o2);
      tc += __shfl_xor(tc, o2);
    }
    __shared__ double smn2[4], smc2[4];
    if (lane == 0) { smn2[w] = tn; smc2[w] = tc; }
    __syncthreads();
    if (t == 0) {
      double fn = smn2[0] + smn2[1] + smn2[2] + smn2[3];
      double fc = smc2[0] + smc2[1] + smc2[2] + smc2[3];
      out[0] = ALPHA_ * (-(float)(fn / 1024.0)) + (float)(fc / 4096.0);
    }
  }
}

__global__ void k_sentinel(float* out) {
  if (threadIdx.x == 0) out[0] = 12345.0f;
}

extern "C" void kernel_launch(void* const* d_in, const int* in_sizes, int n_in,
                              void* d_out, int out_size, void* d_ws, size_t ws_size,
                              hipStream_t stream) {
  const float* predicts = (const float*)d_in[0];
  const int* labels = (const int*)d_in[1];
  const float* features = (const float*)d_in[2];

  char* ws = (char*)d_ws;
  const size_t offFeatB = 0;                  // 1 MiB
  const size_t offS1 = 1048576;               // 4096*8*8*4 = 1 MiB
  const size_t offS2 = offS1 + 1048576;       // 1 MiB
  const size_t offP = offS2 + 1048576;        // 128 KiB
  const size_t offCe = offP + 131072;         // 512 doubles
  const size_t offNce = offCe + 4096;         // 128 doubles
  const size_t offCnt = offNce + 1024;        // 1 uint
  const size_t need = offCnt + 64;

  float* out = (float*)d_out;
  if (ws_size < need) {
    k_sentinel<<<1, 64, 0, stream>>>(out);
    return;
  }

  uint16_t* featB = (uint16_t*)(ws + offFeatB);
  float* S1h = (float*)(ws + offS1);
  float* S2h = (float*)(ws + offS2);
  float* P = (float*)(ws + offP);
  double* p_ce = (double*)(ws + offCe);
  double* p_nce = (double*)(ws + offNce);
  unsigned int* counter = (unsigned int*)(ws + offCnt);

  k_prep<<<512, 256, 0, stream>>>(features, predicts, labels, featB, p_ce, counter);
  k_sweep<<<2048, 256, 0, stream>>>(featB, S1h, S2h, P);
  k_post<<<128, 256, 0, stream>>>(S1h, S2h, P, p_ce, p_nce, counter, out);
}